// Round 7
// baseline (244.471 us; speedup 1.0000x reference)
//
#include <hip/hip_runtime.h>

// Problem constants (match reference setup_inputs)
#define BB   64
#define CIN  2048
#define COUT 2048
#define TT   128

// Sparse compaction geometry:
//   pair  = 32 output channels (4 mask row-blocks)  -> 64 pairs
//   slot  = 16 k values (2 mask col-blocks)         -> 128 slots, keep ~0.57
//   window= 16 slots (256 bytes of a row)           -> 8 windows
//   chunk = 4 slots = one MFMA K=64
#define NPAIR 64
#define NWIN  8
#define SLOTW 16

typedef int i32x4 __attribute__((ext_vector_type(4)));

__device__ __forceinline__ void async16(char* lds_dst, const char* g_src) {
    __builtin_amdgcn_global_load_lds(
        (const __attribute__((address_space(1))) void*)g_src,
        (__attribute__((address_space(3))) void*)lds_dst,
        16, 0, 0);
}

// --- prep1: spikes -> i8 A[(b*T+t)][c] via 256ch x 32t LDS transpose tiles
//            + 256 ballot blocks (bid>=2048): keep-bit table kb[256][4] u64
__global__ void prep1(const float* __restrict__ spikes,
                      const float* __restrict__ msk,
                      char* __restrict__ A,
                      unsigned long long* __restrict__ kb) {
    int bid = blockIdx.x;
    int tid = threadIdx.x;

    if (bid >= 2048) {
        int rb = bid - 2048;
        bool keep = (msk[(size_t)(rb * 8) * CIN + tid * 8] != 0.f);
        unsigned long long m = __ballot(keep);
        if ((tid & 63) == 0) kb[rb * 4 + (tid >> 6)] = m;
        return;
    }

    __shared__ float tile[32][256];            // 32 KB
    int cg = bid & 7, tg = (bid >> 3) & 3, b = bid >> 5;
    int c0 = cg * 256, t0 = tg * 32;

    {
        const float* src = spikes + ((size_t)b * CIN + c0 + tid) * TT + t0;
#pragma unroll
        for (int j = 0; j < 8; ++j) {
            float4 v = *(const float4*)(src + j * 4);
            tile[j * 4 + 0][tid] = v.x;
            tile[j * 4 + 1][tid] = v.y;
            tile[j * 4 + 2][tid] = v.z;
            tile[j * 4 + 3][tid] = v.w;
        }
    }
    __syncthreads();

    const int cq = tid & 63, tw = tid >> 6;
#pragma unroll
    for (int s2 = 0; s2 < 8; ++s2) {
        int t = s2 * 4 + tw;
        float4 v = *(const float4*)&tile[t][cq * 4];   // contiguous 1KB/wave
        unsigned pk = (v.x != 0.f ? 0x1u : 0u) | (v.y != 0.f ? 0x100u : 0u) |
                      (v.z != 0.f ? 0x10000u : 0u) | (v.w != 0.f ? 0x1000000u : 0u);
        *(unsigned*)(A + ((size_t)(b * TT) + t0 + t) * CIN + c0 + cq * 4) = pk;
    }
}

// --- prep2: per-(pair,window) meta from kb; 512 entries, two-level scan;
//            fill compacted B (frag-ready [slot][col 0..31][16B]) + slot lists
__global__ void prep2(const float* __restrict__ w,
                      const float* __restrict__ msk,
                      const unsigned long long* __restrict__ kb,
                      char* __restrict__ Bc,
                      unsigned short* __restrict__ lst,
                      unsigned* __restrict__ ofs_g,
                      unsigned* __restrict__ nch_g) {
    __shared__ unsigned sbm[256];              // [pair*4 + word] 32-slot masks
    __shared__ unsigned short snch[512];
    __shared__ unsigned sofs[512];
    __shared__ unsigned partial[64];
    __shared__ short skl[SLOTW];
    const int tid = threadIdx.x;
    const int pw = blockIdx.x;                 // p*8 + wdw

    {
        int p = tid >> 2, j = tid & 3;
        unsigned long long r = kb[(4 * p + 0) * 4 + j] | kb[(4 * p + 1) * 4 + j] |
                               kb[(4 * p + 2) * 4 + j] | kb[(4 * p + 3) * 4 + j];
        unsigned long long t2 = r | (r >> 1);
        unsigned bm = 0u;
#pragma unroll
        for (int s = 0; s < 32; ++s)
            bm |= (unsigned)((t2 >> (2 * s)) & 1ull) << s;
        sbm[tid] = bm;                         // 32 slots of (pair p, word j)
    }
    __syncthreads();
    for (int e = tid; e < 512; e += 256) {     // entry e = p*8 + wdw
        int p = e >> 3, wdw = e & 7;
        unsigned bm16 = (sbm[p * 4 + (wdw >> 1)] >> ((wdw & 1) * 16)) & 0xFFFFu;
        snch[e] = (unsigned short)((__popc(bm16) + 3) >> 2);
    }
    __syncthreads();
    if (tid < 64) {                            // two-level exclusive scan
        unsigned run = 0;
        for (int k = 0; k < 8; ++k) run += (unsigned)snch[tid * 8 + k] * 4;
        partial[tid] = run;
    }
    __syncthreads();
    if (tid == 0) {
        unsigned run = 0;
        for (int i = 0; i < 64; ++i) { unsigned t = partial[i]; partial[i] = run; run += t; }
    }
    __syncthreads();
    if (tid < 64) {
        unsigned run = partial[tid];
        for (int k = 0; k < 8; ++k) { sofs[tid * 8 + k] = run; run += (unsigned)snch[tid * 8 + k] * 4; }
    }
    __syncthreads();
    if (tid == 0) {
        ofs_g[pw] = sofs[pw];
        nch_g[pw] = snch[pw];
        unsigned bm16 = (sbm[(pw >> 3) * 4 + ((pw & 7) >> 1)] >> (((pw & 7) & 1) * 16)) & 0xFFFFu;
        unsigned rem = bm16;
        unsigned ns = (unsigned)snch[pw] * 4;
        unsigned o0 = sofs[pw];
        for (unsigned j = 0; j < ns; ++j) {
            int kl = -1;
            if (rem) { kl = __ffs(rem) - 1; rem &= rem - 1u; }
            skl[j] = (short)kl;
            lst[o0 + j] = (unsigned short)(kl >= 0 ? kl : 0);
        }
    }
    __syncthreads();

    const int p = pw >> 3, wdw = pw & 7;
    const unsigned o = sofs[pw];
    const unsigned nslots = (unsigned)snch[pw] * 4;

    const int col = (tid & 127) >> 2, q = tid & 3;
    const unsigned jo = tid >> 7;              // 0 or 1: two slots in flight
    for (unsigned j0 = 0; j0 < nslots; j0 += 2) {
        unsigned j = j0 + jo;
        if (j < nslots) {
            int kl = skl[j];
            unsigned pk = 0u;
            if (kl >= 0) {
                int kk = wdw * SLOTW + kl;     // global k16 slot
                size_t base = (size_t)(p * 32 + col) * CIN + kk * 16 + q * 4;
                float4 a = *(const float4*)(w + base);
                float4 m = *(const float4*)(msk + base);
                int b0 = (int)(char)(int)(a.x * m.x);
                int b1 = (int)(char)(int)(a.y * m.y);
                int b2 = (int)(char)(int)(a.z * m.z);
                int b3 = (int)(char)(int)(a.w * m.w);
                pk = (unsigned)((b0 & 0xFF) | ((b1 & 0xFF) << 8) | ((b2 & 0xFF) << 16) | (b3 << 24));
            }
            *(unsigned*)(Bc + (size_t)(o + j) * 512 + col * 16 + q * 4) = pk;
        }
    }
}

// --- Sparse-gather GEMM: BM=128, BN=256 (1 pair/wave), BK=256, dbuf A,
//     in-register LIF scan via shfl (no LDS C buffer) -> 2 blocks/CU,
//     all 512 blocks co-resident ---
__global__ void __launch_bounds__(512, 4)
snn_gemm_scan(const char* __restrict__ A,     // [8192][2048] i8
              const char* __restrict__ Bc,    // compacted [slot][32][16] i8
              const unsigned short* __restrict__ lst,
              const unsigned* __restrict__ ofs,
              const unsigned* __restrict__ nchv,
              const int* __restrict__ scale_exp,
              const int* __restrict__ thr_exp,
              float* __restrict__ out) {      // [B][COUT][T]
    __shared__ __align__(16) char lds_a[2][128 * 256];   // 64 KB dbuf A windows
    __shared__ unsigned short slist[8][NWIN][SLOTW];     // 2 KB, persistent
    __shared__ unsigned smeta_ofs[64];                   // [pl*8 + w]
    __shared__ unsigned smeta_nch[64];
    __shared__ unsigned pb[256 * 4];                     // 4 KB spike bits

    const int tid  = threadIdx.x;
    const int lane = tid & 63;
    const int w    = tid >> 6;        // wave id = pair index 0..7

    // bid = nt*64 + b: XCD = bid%8 = b%8 -> all 8 nt-blocks of one batch
    // co-XCD (A panel fetched once per XCD L2 -- r4/r6 verified mapping)
    const int bid = blockIdx.x;
    const int b  = bid & 63;
    const int nt = bid >> 6;          // 0..7
    const int m0 = b * TT;
    const int p0 = nt * 8;            // global pair base

    const int mrow = lane & 15, kc = lane >> 4;

    // ---- block-persistent meta + slot lists (one-time) ----
    if (tid < 128) {
        int i = tid & 63;             // pl*8 + w
        unsigned g = (p0 + (i >> 3)) * 8 + (i & 7);
        if (tid < 64) smeta_ofs[i] = ofs[g];
        else          smeta_nch[i] = nchv[g];
    }
    {
        int pl = tid >> 6;
        int rest = tid & 63;          // w2*8 + e-pair
        int w2 = rest >> 3, e = (rest & 7) * 2;
        unsigned g = (p0 + pl) * 8 + w2;
        unsigned o = ofs[g];
        *(unsigned*)&slist[pl][w2][e] = *(const unsigned*)(lst + o + e);
    }

    i32x4 acc[8][2] = {};             // [m-frag 0..7][col-frag 0..1]

    // stage A window wdw (128 rows x 256 B) into buffer buf
    auto stage = [&](int wdw, int buf) {
#pragma unroll
        for (int i = 0; i < 4; ++i) {
            int f = i * 512 + tid;
            int row = f >> 4, g0 = f & 15;
            int src = (g0 & ~7) | ((g0 & 7) ^ (row & 7));
            async16(lds_a[buf] + (size_t)f * 16,
                    A + (size_t)(m0 + row) * CIN + wdw * 256 + src * 16);
        }
    };

    stage(0, 0);
    stage(1, 1);
    asm volatile("s_waitcnt vmcnt(4) lgkmcnt(0)" ::: "memory");
    __builtin_amdgcn_s_barrier();

#pragma unroll
    for (int wdw = 0; wdw < NWIN; ++wdw) {
        const char* sa = lds_a[wdw & 1];
        const unsigned o   = smeta_ofs[w * 8 + wdw];
        const unsigned nch = smeta_nch[w * 8 + wdw];
        const unsigned short* Lp = &slist[w][wdw][0];
        const char* bbase = Bc + (size_t)o * 512 + mrow * 16 + (size_t)kc * 512;

        if (nch) {
            // distance-1 pipeline: next chunk's (kk,b0,b1) prefetched
            int   kkN = (int)Lp[kc];
            i32x4 b0N = *(const i32x4*)bbase;
            i32x4 b1N = *(const i32x4*)(bbase + 256);
            for (unsigned c = 0; c < nch; ++c) {
                const int   kkC = kkN;
                const i32x4 b0C = b0N, b1C = b1N;
                if (c + 1 < nch) {
                    kkN = (int)Lp[(c + 1) * 4 + kc];
                    b0N = *(const i32x4*)(bbase + (size_t)(c + 1) * 2048);
                    b1N = *(const i32x4*)(bbase + (size_t)(c + 1) * 2048 + 256);
                }
                const int swz = mrow * 256 + ((kkC ^ (mrow & 7)) << 4);
                i32x4 av[4];
#pragma unroll
                for (int mf = 0; mf < 4; ++mf)
                    av[mf] = *(const i32x4*)(sa + mf * 4096 + swz);
#pragma unroll
                for (int mf = 0; mf < 4; ++mf) {
                    acc[mf][0] = __builtin_amdgcn_mfma_i32_16x16x64_i8(
                        av[mf], b0C, acc[mf][0], 0, 0, 0);
                    acc[mf][1] = __builtin_amdgcn_mfma_i32_16x16x64_i8(
                        av[mf], b1C, acc[mf][1], 0, 0, 0);
                }
#pragma unroll
                for (int mf = 0; mf < 4; ++mf)
                    av[mf] = *(const i32x4*)(sa + (4 + mf) * 4096 + swz);
#pragma unroll
                for (int mf = 0; mf < 4; ++mf) {
                    acc[4 + mf][0] = __builtin_amdgcn_mfma_i32_16x16x64_i8(
                        av[mf], b0C, acc[4 + mf][0], 0, 0, 0);
                    acc[4 + mf][1] = __builtin_amdgcn_mfma_i32_16x16x64_i8(
                        av[mf], b1C, acc[4 + mf][1], 0, 0, 0);
                }
            }
        }

        __builtin_amdgcn_s_barrier();          // all waves done reading buf
        if (wdw + 2 < NWIN) {
            stage(wdw + 2, wdw & 1);           // overwrite just-freed buffer
            asm volatile("s_waitcnt vmcnt(4)" ::: "memory");  // stage(wdw+1) done
            __builtin_amdgcn_s_barrier();
        } else if (wdw + 1 < NWIN) {
            asm volatile("s_waitcnt vmcnt(0)" ::: "memory");
            __builtin_amdgcn_s_barrier();
        }
    }

    // ---- Epilogue: in-register LIF scan, all 8 waves concurrent ----
    // acc C/D layout: value at (t = mf*16 + hi*4 + r, col = cf*16 + ch)
    // lives in lane hi*16+ch, register acc[mf][cf][r].
    // Owner lanes: grp0 (lanes 0..15) scan cf=0, grp1 (16..31) scan cf=1.
    const float thr = exp2f((float)thr_exp[0]);
    const int ch = lane & 15;
    const int grp = lane >> 4;
    const float myscale = exp2f((float)scale_exp[nt * 256 + w * 32 + (grp & 1) * 16 + ch]);

    float a = 0.f;
    unsigned bq[4] = {0u, 0u, 0u, 0u};
#pragma unroll
    for (int mf = 0; mf < 8; ++mf)
#pragma unroll
        for (int hi = 0; hi < 4; ++hi) {
            const int src = hi * 16 + ch;
#pragma unroll
            for (int r = 0; r < 4; ++r) {
                int s0 = __shfl(acc[mf][0][r], src);
                int s1 = __shfl(acc[mf][1][r], src);
                float v = (float)((grp & 1) ? s1 : s0);
                a = fmaf(v, myscale, a);
                const int t = mf * 16 + hi * 4 + r;
                unsigned sp = (a >= thr) ? 1u : 0u;
                if (sp) a = 0.f;
                bq[t >> 5] |= sp << (t & 31);
            }
        }
    if (grp < 2) {
        int cg = w * 32 + grp * 16 + ch;
#pragma unroll
        for (int q = 0; q < 4; ++q) pb[cg * 4 + q] = bq[q];
    }
    __syncthreads();

    // coalesced float4 stores: out[b][nt*256 + co][t], all 256 channels
    const int t4 = tid & 31, u = tid >> 5;
#pragma unroll
    for (int s2 = 0; s2 < 16; ++s2) {
        int co = s2 * 16 + u;
        unsigned wb  = pb[co * 4 + (t4 >> 3)];
        unsigned nib = (wb >> ((t4 & 7) * 4)) & 0xFu;
        float4 v;
        v.x = (float)(nib & 1u);
        v.y = (float)((nib >> 1) & 1u);
        v.z = (float)((nib >> 2) & 1u);
        v.w = (float)((nib >> 3) & 1u);
        *(float4*)(out + (size_t)(b * COUT + nt * 256 + co) * TT + t4 * 4) = v;
    }
}

extern "C" void kernel_launch(void* const* d_in, const int* in_sizes, int n_in,
                              void* d_out, int out_size, void* d_ws, size_t ws_size,
                              hipStream_t stream) {
    const float* spikes  = (const float*)d_in[0];
    const float* weights = (const float*)d_in[1];
    const float* mask    = (const float*)d_in[2];
    const int*   scale_e = (const int*)d_in[3];
    const int*   thr_e   = (const int*)d_in[4];
    float* out = (float*)d_out;

    char* ws = (char*)d_ws;
    char*               Ai8  = ws;                                     // 16 MB
    char*               Bc   = ws + 16777216;                          // 4 MB + pad
    unsigned short*     lstp = (unsigned short*)(ws + 20973568);       // 16.4 KB
    unsigned*           ofsp = (unsigned*)(ws + 20990016);             // 2 KB
    unsigned*           nchp = (unsigned*)(ws + 20992064);             // 2 KB
    unsigned long long* kbp  = (unsigned long long*)(ws + 20994112);   // 8 KB

    prep1<<<2048 + 256, 256, 0, stream>>>(spikes, mask, Ai8, kbp);
    prep2<<<NPAIR * NWIN, 256, 0, stream>>>(weights, mask, kbp, Bc, lstp, ofsp, nchp);
    snn_gemm_scan<<<8 * BB, 512, 0, stream>>>(Ai8, Bc, lstp, ofsp, nchp,
                                              scale_e, thr_e, out);
}

// Round 8
// 210.946 us; speedup vs baseline: 1.1589x; 1.1589x over previous
//
#include <hip/hip_runtime.h>

// Problem constants (match reference setup_inputs)
#define BB   64
#define CIN  2048
#define COUT 2048
#define TT   128

// Sparse compaction geometry:
//   pair  = 32 output channels (4 mask row-blocks)  -> 64 pairs
//   slot  = 16 k values (2 mask col-blocks)         -> 128 slots, keep ~0.57
//   window= 16 slots (256 bytes of a row)           -> 8 windows
//   chunk = 4 slots = one MFMA K=64
#define NPAIR 64
#define NWIN  8
#define SLOTW 16

typedef int i32x4 __attribute__((ext_vector_type(4)));

__device__ __forceinline__ void async16(char* lds_dst, const char* g_src) {
    __builtin_amdgcn_global_load_lds(
        (const __attribute__((address_space(1))) void*)g_src,
        (__attribute__((address_space(3))) void*)lds_dst,
        16, 0, 0);
}

// --- prep1: spikes -> i8 A[(b*T+t)][c] via 256ch x 32t LDS transpose tiles
//            + 256 ballot blocks (bid>=2048): keep-bit table kb[256][4] u64
__global__ void prep1(const float* __restrict__ spikes,
                      const float* __restrict__ msk,
                      char* __restrict__ A,
                      unsigned long long* __restrict__ kb) {
    int bid = blockIdx.x;
    int tid = threadIdx.x;

    if (bid >= 2048) {
        int rb = bid - 2048;
        bool keep = (msk[(size_t)(rb * 8) * CIN + tid * 8] != 0.f);
        unsigned long long m = __ballot(keep);
        if ((tid & 63) == 0) kb[rb * 4 + (tid >> 6)] = m;
        return;
    }

    __shared__ float tile[32][256];            // 32 KB
    int cg = bid & 7, tg = (bid >> 3) & 3, b = bid >> 5;
    int c0 = cg * 256, t0 = tg * 32;

    {
        const float* src = spikes + ((size_t)b * CIN + c0 + tid) * TT + t0;
#pragma unroll
        for (int j = 0; j < 8; ++j) {
            float4 v = *(const float4*)(src + j * 4);
            tile[j * 4 + 0][tid] = v.x;
            tile[j * 4 + 1][tid] = v.y;
            tile[j * 4 + 2][tid] = v.z;
            tile[j * 4 + 3][tid] = v.w;
        }
    }
    __syncthreads();

    const int cq = tid & 63, tw = tid >> 6;
#pragma unroll
    for (int s2 = 0; s2 < 8; ++s2) {
        int t = s2 * 4 + tw;
        float4 v = *(const float4*)&tile[t][cq * 4];   // contiguous 1KB/wave
        unsigned pk = (v.x != 0.f ? 0x1u : 0u) | (v.y != 0.f ? 0x100u : 0u) |
                      (v.z != 0.f ? 0x10000u : 0u) | (v.w != 0.f ? 0x1000000u : 0u);
        *(unsigned*)(A + ((size_t)(b * TT) + t0 + t) * CIN + c0 + cq * 4) = pk;
    }
}

// --- prep2: per-(pair,window) meta from kb; 512 entries, two-level scan;
//            fill compacted B (frag-ready [slot][col 0..31][16B]) + slot lists
__global__ void prep2(const float* __restrict__ w,
                      const float* __restrict__ msk,
                      const unsigned long long* __restrict__ kb,
                      char* __restrict__ Bc,
                      unsigned short* __restrict__ lst,
                      unsigned* __restrict__ ofs_g,
                      unsigned* __restrict__ nch_g) {
    __shared__ unsigned sbm[256];              // [pair*4 + word] 32-slot masks
    __shared__ unsigned short snch[512];
    __shared__ unsigned sofs[512];
    __shared__ unsigned partial[64];
    __shared__ short skl[SLOTW];
    const int tid = threadIdx.x;
    const int pw = blockIdx.x;                 // p*8 + wdw

    {
        int p = tid >> 2, j = tid & 3;
        unsigned long long r = kb[(4 * p + 0) * 4 + j] | kb[(4 * p + 1) * 4 + j] |
                               kb[(4 * p + 2) * 4 + j] | kb[(4 * p + 3) * 4 + j];
        unsigned long long t2 = r | (r >> 1);
        unsigned bm = 0u;
#pragma unroll
        for (int s = 0; s < 32; ++s)
            bm |= (unsigned)((t2 >> (2 * s)) & 1ull) << s;
        sbm[tid] = bm;                         // 32 slots of (pair p, word j)
    }
    __syncthreads();
    for (int e = tid; e < 512; e += 256) {     // entry e = p*8 + wdw
        int p = e >> 3, wdw = e & 7;
        unsigned bm16 = (sbm[p * 4 + (wdw >> 1)] >> ((wdw & 1) * 16)) & 0xFFFFu;
        snch[e] = (unsigned short)((__popc(bm16) + 3) >> 2);
    }
    __syncthreads();
    if (tid < 64) {                            // two-level exclusive scan
        unsigned run = 0;
        for (int k = 0; k < 8; ++k) run += (unsigned)snch[tid * 8 + k] * 4;
        partial[tid] = run;
    }
    __syncthreads();
    if (tid == 0) {
        unsigned run = 0;
        for (int i = 0; i < 64; ++i) { unsigned t = partial[i]; partial[i] = run; run += t; }
    }
    __syncthreads();
    if (tid < 64) {
        unsigned run = partial[tid];
        for (int k = 0; k < 8; ++k) { sofs[tid * 8 + k] = run; run += (unsigned)snch[tid * 8 + k] * 4; }
    }
    __syncthreads();
    if (tid == 0) {
        ofs_g[pw] = sofs[pw];
        nch_g[pw] = snch[pw];
        unsigned bm16 = (sbm[(pw >> 3) * 4 + ((pw & 7) >> 1)] >> (((pw & 7) & 1) * 16)) & 0xFFFFu;
        unsigned rem = bm16;
        unsigned ns = (unsigned)snch[pw] * 4;
        unsigned o0 = sofs[pw];
        for (unsigned j = 0; j < ns; ++j) {
            int kl = -1;
            if (rem) { kl = __ffs(rem) - 1; rem &= rem - 1u; }
            skl[j] = (short)kl;
            lst[o0 + j] = (unsigned short)(kl >= 0 ? kl : 0);
        }
    }
    __syncthreads();

    const int p = pw >> 3, wdw = pw & 7;
    const unsigned o = sofs[pw];
    const unsigned nslots = (unsigned)snch[pw] * 4;

    const int col = (tid & 127) >> 2, q = tid & 3;
    const unsigned jo = tid >> 7;              // 0 or 1: two slots in flight
    for (unsigned j0 = 0; j0 < nslots; j0 += 2) {
        unsigned j = j0 + jo;
        if (j < nslots) {
            int kl = skl[j];
            unsigned pk = 0u;
            if (kl >= 0) {
                int kk = wdw * SLOTW + kl;     // global k16 slot
                size_t base = (size_t)(p * 32 + col) * CIN + kk * 16 + q * 4;
                float4 a = *(const float4*)(w + base);
                float4 m = *(const float4*)(msk + base);
                int b0 = (int)(char)(int)(a.x * m.x);
                int b1 = (int)(char)(int)(a.y * m.y);
                int b2 = (int)(char)(int)(a.z * m.z);
                int b3 = (int)(char)(int)(a.w * m.w);
                pk = (unsigned)((b0 & 0xFF) | ((b1 & 0xFF) << 8) | ((b2 & 0xFF) << 16) | (b3 << 24));
            }
            *(unsigned*)(Bc + (size_t)(o + j) * 512 + col * 16 + q * 4) = pk;
        }
    }
}

// --- Sparse-gather GEMM: BM=128, BN=256 (1 pair/wave), BK=256, dbuf A,
//     in-register LIF scan via shfl (no LDS C buffer).
//     __launch_bounds__(512, 2): arg2 = min BLOCKS/CU (CUDA semantics,
//     confirmed r7: (512,4) capped VGPR at 64 -> catastrophic spill).
//     2 blocks x 8 waves = 16 waves/CU -> 128-VGPR cap; need ~110 -> fits.
__global__ void __launch_bounds__(512, 2)
snn_gemm_scan(const char* __restrict__ A,     // [8192][2048] i8
              const char* __restrict__ Bc,    // compacted [slot][32][16] i8
              const unsigned short* __restrict__ lst,
              const unsigned* __restrict__ ofs,
              const unsigned* __restrict__ nchv,
              const int* __restrict__ scale_exp,
              const int* __restrict__ thr_exp,
              float* __restrict__ out) {      // [B][COUT][T]
    __shared__ __align__(16) char lds_a[2][128 * 256];   // 64 KB dbuf A windows
    __shared__ unsigned short slist[8][NWIN][SLOTW];     // 2 KB, persistent
    __shared__ unsigned smeta_ofs[64];                   // [pl*8 + w]
    __shared__ unsigned smeta_nch[64];
    __shared__ unsigned pb[256 * 4];                     // 4 KB spike bits

    const int tid  = threadIdx.x;
    const int lane = tid & 63;
    const int w    = tid >> 6;        // wave id = pair index 0..7

    // bid = nt*64 + b: XCD = bid%8 = b%8 -> all 8 nt-blocks of one batch
    // co-XCD (A panel fetched once per XCD L2 -- r4/r6 verified mapping)
    const int bid = blockIdx.x;
    const int b  = bid & 63;
    const int nt = bid >> 6;          // 0..7
    const int m0 = b * TT;
    const int p0 = nt * 8;            // global pair base

    const int mrow = lane & 15, kc = lane >> 4;

    // ---- block-persistent meta + slot lists (one-time) ----
    if (tid < 128) {
        int i = tid & 63;             // pl*8 + w
        unsigned g = (p0 + (i >> 3)) * 8 + (i & 7);
        if (tid < 64) smeta_ofs[i] = ofs[g];
        else          smeta_nch[i] = nchv[g];
    }
    {
        int pl = tid >> 6;
        int rest = tid & 63;          // w2*8 + e-pair
        int w2 = rest >> 3, e = (rest & 7) * 2;
        unsigned g = (p0 + pl) * 8 + w2;
        unsigned o = ofs[g];
        *(unsigned*)&slist[pl][w2][e] = *(const unsigned*)(lst + o + e);
    }

    i32x4 acc[8][2] = {};             // [m-frag 0..7][col-frag 0..1]

    // stage A window wdw (128 rows x 256 B) into buffer buf
    auto stage = [&](int wdw, int buf) {
#pragma unroll
        for (int i = 0; i < 4; ++i) {
            int f = i * 512 + tid;
            int row = f >> 4, g0 = f & 15;
            int src = (g0 & ~7) | ((g0 & 7) ^ (row & 7));
            async16(lds_a[buf] + (size_t)f * 16,
                    A + (size_t)(m0 + row) * CIN + wdw * 256 + src * 16);
        }
    };

    stage(0, 0);
    stage(1, 1);
    asm volatile("s_waitcnt vmcnt(4) lgkmcnt(0)" ::: "memory");
    __builtin_amdgcn_s_barrier();

#pragma unroll
    for (int wdw = 0; wdw < NWIN; ++wdw) {
        const char* sa = lds_a[wdw & 1];
        const unsigned o   = smeta_ofs[w * 8 + wdw];
        const unsigned nch = smeta_nch[w * 8 + wdw];
        const unsigned short* Lp = &slist[w][wdw][0];
        const char* bbase = Bc + (size_t)o * 512 + mrow * 16 + (size_t)kc * 512;

        if (nch) {
            // distance-1 pipeline: next chunk's (kk,b0,b1) prefetched
            int   kkN = (int)Lp[kc];
            i32x4 b0N = *(const i32x4*)bbase;
            i32x4 b1N = *(const i32x4*)(bbase + 256);
            for (unsigned c = 0; c < nch; ++c) {
                const int   kkC = kkN;
                const i32x4 b0C = b0N, b1C = b1N;
                if (c + 1 < nch) {
                    kkN = (int)Lp[(c + 1) * 4 + kc];
                    b0N = *(const i32x4*)(bbase + (size_t)(c + 1) * 2048);
                    b1N = *(const i32x4*)(bbase + (size_t)(c + 1) * 2048 + 256);
                }
                const int swz = mrow * 256 + ((kkC ^ (mrow & 7)) << 4);
                i32x4 av[4];
#pragma unroll
                for (int mf = 0; mf < 4; ++mf)
                    av[mf] = *(const i32x4*)(sa + mf * 4096 + swz);
#pragma unroll
                for (int mf = 0; mf < 4; ++mf) {
                    acc[mf][0] = __builtin_amdgcn_mfma_i32_16x16x64_i8(
                        av[mf], b0C, acc[mf][0], 0, 0, 0);
                    acc[mf][1] = __builtin_amdgcn_mfma_i32_16x16x64_i8(
                        av[mf], b1C, acc[mf][1], 0, 0, 0);
                }
#pragma unroll
                for (int mf = 0; mf < 4; ++mf)
                    av[mf] = *(const i32x4*)(sa + (4 + mf) * 4096 + swz);
#pragma unroll
                for (int mf = 0; mf < 4; ++mf) {
                    acc[4 + mf][0] = __builtin_amdgcn_mfma_i32_16x16x64_i8(
                        av[mf], b0C, acc[4 + mf][0], 0, 0, 0);
                    acc[4 + mf][1] = __builtin_amdgcn_mfma_i32_16x16x64_i8(
                        av[mf], b1C, acc[4 + mf][1], 0, 0, 0);
                }
            }
        }

        __builtin_amdgcn_s_barrier();          // all waves done reading buf
        if (wdw + 2 < NWIN) {
            stage(wdw + 2, wdw & 1);           // overwrite just-freed buffer
            asm volatile("s_waitcnt vmcnt(4)" ::: "memory");  // stage(wdw+1) done
            __builtin_amdgcn_s_barrier();
        } else if (wdw + 1 < NWIN) {
            asm volatile("s_waitcnt vmcnt(0)" ::: "memory");
            __builtin_amdgcn_s_barrier();
        }
    }

    // ---- Epilogue: in-register LIF scan, all 8 waves concurrent ----
    // acc C/D layout: value at (t = mf*16 + hi*4 + r, col = cf*16 + ch)
    // lives in lane hi*16+ch, register acc[mf][cf][r].
    // Owner lanes: grp0 (lanes 0..15) scan cf=0, grp1 (16..31) scan cf=1.
    const float thr = exp2f((float)thr_exp[0]);
    const int ch = lane & 15;
    const int grp = lane >> 4;
    const float myscale = exp2f((float)scale_exp[nt * 256 + w * 32 + (grp & 1) * 16 + ch]);

    float a = 0.f;
    unsigned bq[4] = {0u, 0u, 0u, 0u};
#pragma unroll
    for (int mf = 0; mf < 8; ++mf)
#pragma unroll
        for (int hi = 0; hi < 4; ++hi) {
            const int src = hi * 16 + ch;
#pragma unroll
            for (int r = 0; r < 4; ++r) {
                int s0 = __shfl(acc[mf][0][r], src);
                int s1 = __shfl(acc[mf][1][r], src);
                float v = (float)((grp & 1) ? s1 : s0);
                a = fmaf(v, myscale, a);
                const int t = mf * 16 + hi * 4 + r;
                unsigned sp = (a >= thr) ? 1u : 0u;
                if (sp) a = 0.f;
                bq[t >> 5] |= sp << (t & 31);
            }
        }
    if (grp < 2) {
        int cg = w * 32 + grp * 16 + ch;
#pragma unroll
        for (int q = 0; q < 4; ++q) pb[cg * 4 + q] = bq[q];
    }
    __syncthreads();

    // coalesced float4 stores: out[b][nt*256 + co][t], all 256 channels
    const int t4 = tid & 31, u = tid >> 5;
#pragma unroll
    for (int s2 = 0; s2 < 16; ++s2) {
        int co = s2 * 16 + u;
        unsigned wb  = pb[co * 4 + (t4 >> 3)];
        unsigned nib = (wb >> ((t4 & 7) * 4)) & 0xFu;
        float4 v;
        v.x = (float)(nib & 1u);
        v.y = (float)((nib >> 1) & 1u);
        v.z = (float)((nib >> 2) & 1u);
        v.w = (float)((nib >> 3) & 1u);
        *(float4*)(out + (size_t)(b * COUT + nt * 256 + co) * TT + t4 * 4) = v;
    }
}

extern "C" void kernel_launch(void* const* d_in, const int* in_sizes, int n_in,
                              void* d_out, int out_size, void* d_ws, size_t ws_size,
                              hipStream_t stream) {
    const float* spikes  = (const float*)d_in[0];
    const float* weights = (const float*)d_in[1];
    const float* mask    = (const float*)d_in[2];
    const int*   scale_e = (const int*)d_in[3];
    const int*   thr_e   = (const int*)d_in[4];
    float* out = (float*)d_out;

    char* ws = (char*)d_ws;
    char*               Ai8  = ws;                                     // 16 MB
    char*               Bc   = ws + 16777216;                          // 4 MB + pad
    unsigned short*     lstp = (unsigned short*)(ws + 20973568);       // 16.4 KB
    unsigned*           ofsp = (unsigned*)(ws + 20990016);             // 2 KB
    unsigned*           nchp = (unsigned*)(ws + 20992064);             // 2 KB
    unsigned long long* kbp  = (unsigned long long*)(ws + 20994112);   // 8 KB

    prep1<<<2048 + 256, 256, 0, stream>>>(spikes, mask, Ai8, kbp);
    prep2<<<NPAIR * NWIN, 256, 0, stream>>>(weights, mask, kbp, Bc, lstp, ofsp, nchp);
    snn_gemm_scan<<<8 * BB, 512, 0, stream>>>(Ai8, Bc, lstp, ofsp, nchp,
                                              scale_e, thr_e, out);
}